// Round 3
// baseline (15631.149 us; speedup 1.0000x reference)
//
#include <hip/hip_runtime.h>
#include <math.h>

// EntNetHead: T=256 sequential steps, B=64 batches, H=768, K=5 memory blocks, L=3.
// Persistent kernel, 256 WGs (1/CU, forced by 149KB LDS), 8 batch-groups x 32
// column-slice WGs. U,W column slices cached in LDS once. h state (raw,
// pre-normalization) double-buffered in a __device__ global; one atomic group
// barrier per step; normalization folded into every read.
// R2 delta vs R1: unified float4 load pattern for ALL per-batch work -> every
// wave computes complete dot products, eliminating the cross-wave LDS combine
// and all per-batch __syncthreads (LDS is read-only in the main loop).

#define T_STEPS 256
#define B_SZ    64
#define H_DIM   768
#define K_BLK   5
#define L_OUT   3
#define EPSV    1e-8f

#define NGROUP  8      // batch groups
#define WPG     32     // workgroups per group (column slices)
#define M_B     8      // batches per group
#define COLS    24     // output columns owned per WG (32*24 = 768)
#define NWG     (NGROUP*WPG)   // 256 == #CUs
#define NTHR    256
#define LDH     (H_DIM+4)      // pad: float4 alignment preserved, banks shifted

// raw (unnormalized) h state, double buffered: 2*64*5*768*4B = 1.97 MB
__device__ float        g_h[2][B_SZ][K_BLK][H_DIM];
__device__ unsigned int g_bar[NGROUP*32];   // one counter per group, 128B apart

__global__ void reset_bar() {
  int i = threadIdx.x;
  if (i < NGROUP*32) g_bar[i] = 0u;
}

__device__ __forceinline__ void group_barrier(unsigned int* cnt, unsigned int target) {
  __syncthreads();                       // drain + workgroup sync
  if (threadIdx.x == 0) {
    __threadfence();                     // release
    atomicAdd(cnt, 1u);
    while (__hip_atomic_load(cnt, __ATOMIC_RELAXED, __HIP_MEMORY_SCOPE_AGENT) < target)
      __builtin_amdgcn_s_sleep(2);
    __threadfence();                     // acquire
  }
  __syncthreads();
}

extern "C" __global__ void __launch_bounds__(NTHR, 1)
entnet_main(const float* __restrict__ fs, const float* __restrict__ fe,
            const float* __restrict__ keys, const float* __restrict__ U,
            const float* __restrict__ V, const float* __restrict__ W,
            const float* __restrict__ alpha, const float* __restrict__ Wout,
            const float* __restrict__ bout, float* __restrict__ out)
{
  __shared__ float U_lds[COLS][LDH];     // 74.1 KB
  __shared__ float W_lds[COLS][LDH];     // 74.1 KB
  __shared__ float keyV_lds[K_BLK][COLS];

  const int tid  = threadIdx.x;
  const int wgid = blockIdx.x;
  const int G    = wgid & 7;             // batch group
  const int g    = wgid >> 3;            // column slice 0..31
  const int c0   = g * COLS;
  const int b0   = G * M_B;
  const float alpha_v = alpha[0];
  const int dl = tid & 63, cg = tid >> 6;  // lane, wave; wave owns cols [6cg,6cg+6)

  // ---- prologue: cache U/W column slices in LDS ----
  for (int idx = tid; idx < COLS*H_DIM; idx += NTHR) {
    int d = idx / COLS, c = idx % COLS;
    U_lds[c][d] = U[(size_t)d*H_DIM + c0 + c];
    W_lds[c][d] = W[(size_t)d*H_DIM + c0 + c];
  }
  // keyV[k][c] = keys[k,:] @ V[:, c0+c]  (step-invariant)
  if (tid < K_BLK*COLS) {
    int k = tid / COLS, c = tid % COLS;
    float acc = 0.f;
    for (int d = 0; d < H_DIM; ++d)
      acc = fmaf(keys[k*H_DIM + d], V[(size_t)d*H_DIM + c0 + c], acc);
    keyV_lds[k][c] = acc;
  }
  // h init: buf0 = keys (reference h0 is NOT normalized)
  for (int idx = tid; idx < M_B*K_BLK*COLS; idx += NTHR) {
    int bi = idx / (K_BLK*COLS); int rr = idx % (K_BLK*COLS);
    int k = rr / COLS, c = rr % COLS;
    g_h[0][b0+bi][k][c0 + c] = keys[k*H_DIM + c0 + c];
  }

  // keys in float4 pattern, step-invariant -> 60 VGPRs
  float4 kv4[3][K_BLK];
  #pragma unroll
  for (int i = 0; i < 3; ++i) {
    const int d = (dl << 2) + i*256;
    #pragma unroll
    for (int k = 0; k < K_BLK; ++k)
      kv4[i][k] = *(const float4*)(keys + k*H_DIM + d);
  }

  unsigned int bar_t = WPG;
  group_barrier(&g_bar[G*32], bar_t);

  // ---- main recurrence (no __syncthreads inside: LDS is read-only here) ----
  for (int t = 0; t < T_STEPS; ++t) {
    const int cur = t & 1, nxt = cur ^ 1;
    const float* sbase = fs + (size_t)t*B_SZ*H_DIM;
    const float* qbase = fe + (size_t)(t > 0 ? (t-1) : 0)*B_SZ*H_DIM;

    for (int bi = 0; bi < M_B; ++bi) {
      const int b = b0 + bi;
      const float* r = &g_h[cur][b][0][0];        // raw h after step t-1
      const float* s = sbase + (size_t)b*H_DIM;
      const float* q = qbase + (size_t)b*H_DIM;   // q_{t-1}; dummy at t==0

      // ---- unified loads: each wave covers the full d-range ----
      float4 rv[3][K_BLK], sv4[3], qv4[3];
      #pragma unroll
      for (int i = 0; i < 3; ++i) {
        const int d = (dl << 2) + i*256;
        #pragma unroll
        for (int k = 0; k < K_BLK; ++k)
          rv[i][k] = *(const float4*)(r + k*H_DIM + d);
        sv4[i] = *(const float4*)(s + d);
        qv4[i] = *(const float4*)(q + d);
      }

      // ---- dots: ss=h.h, sh=s.h, qh=q.h, sk=s.keys (per-wave complete) ----
      float ss[K_BLK]={0,0,0,0,0}, sh[K_BLK]={0,0,0,0,0};
      float qh[K_BLK]={0,0,0,0,0}, sk[K_BLK]={0,0,0,0,0};
      #pragma unroll
      for (int i = 0; i < 3; ++i) {
        const float4 sv = sv4[i], qv = qv4[i];
        #pragma unroll
        for (int k = 0; k < K_BLK; ++k) {
          const float4 rk = rv[i][k], kk4 = kv4[i][k];
          ss[k] = fmaf(rk.x, rk.x, fmaf(rk.y, rk.y, fmaf(rk.z, rk.z, fmaf(rk.w, rk.w, ss[k]))));
          sh[k] = fmaf(sv.x, rk.x, fmaf(sv.y, rk.y, fmaf(sv.z, rk.z, fmaf(sv.w, rk.w, sh[k]))));
          qh[k] = fmaf(qv.x, rk.x, fmaf(qv.y, rk.y, fmaf(qv.z, rk.z, fmaf(qv.w, rk.w, qh[k]))));
          sk[k] = fmaf(sv.x, kk4.x, fmaf(sv.y, kk4.y, fmaf(sv.z, kk4.z, fmaf(sv.w, kk4.w, sk[k]))));
        }
      }
      #pragma unroll
      for (int off = 1; off < 64; off <<= 1) {
        #pragma unroll
        for (int k = 0; k < K_BLK; ++k) {
          ss[k] += __shfl_xor(ss[k], off);
          sh[k] += __shfl_xor(sh[k], off);
          qh[k] += __shfl_xor(qh[k], off);
          sk[k] += __shfl_xor(sk[k], off);
        }
      }
      // every lane now holds complete dots for all 5 blocks

      // pred for step t-1 (scores use normalized r), slice-0 WGs, lanes 0..2
      if (g == 0 && t > 0 && tid < L_OUT) {
        float p = bout[tid];
        #pragma unroll
        for (int k = 0; k < K_BLK; ++k)
          p = fmaf(qh[k] / (sqrtf(ss[k]) + EPSV), Wout[k*L_OUT + tid], p);
        out[(size_t)((t-1)*B_SZ + b)*L_OUT + tid] = p;
      }

      // ---- Phase B: hU (raw) and sW on our 24 columns ----
      float acc[K_BLK][6] = {}; float accW[6] = {};
      #pragma unroll
      for (int i = 0; i < 3; ++i) {
        const int d = (dl << 2) + i*256;
        const float4 sv = sv4[i];
        #pragma unroll
        for (int j = 0; j < 6; ++j) {
          const int c = cg*6 + j;
          const float4 u = *(const float4*)&U_lds[c][d];
          #pragma unroll
          for (int k = 0; k < K_BLK; ++k) {
            const float4 rk = rv[i][k];
            acc[k][j] = fmaf(rk.x, u.x, fmaf(rk.y, u.y, fmaf(rk.z, u.z, fmaf(rk.w, u.w, acc[k][j]))));
          }
          const float4 w4 = *(const float4*)&W_lds[c][d];
          accW[j] = fmaf(sv.x, w4.x, fmaf(sv.y, w4.y, fmaf(sv.z, w4.z, fmaf(sv.w, w4.w, accW[j]))));
        }
      }
      #pragma unroll
      for (int off = 1; off < 64; off <<= 1) {
        #pragma unroll
        for (int j = 0; j < 6; ++j) {
          #pragma unroll
          for (int k = 0; k < K_BLK; ++k) acc[k][j] += __shfl_xor(acc[k][j], off);
          accW[j] += __shfl_xor(accW[j], off);
        }
      }
      if (dl < 30) {
        const int kk = dl / 6, jj = dl - kk*6;
        // compile-time-unrolled selects (avoid runtime register indexing)
        float v = 0.f, vw = 0.f, ssk = 0.f, shk = 0.f, skk = 0.f;
        #pragma unroll
        for (int k2 = 0; k2 < K_BLK; ++k2) {
          #pragma unroll
          for (int j2 = 0; j2 < 6; ++j2)
            v = (kk == k2 && jj == j2) ? acc[k2][j2] : v;
          ssk = (kk == k2) ? ss[k2] : ssk;
          shk = (kk == k2) ? sh[k2] : shk;
          skk = (kk == k2) ? sk[k2] : skk;
        }
        #pragma unroll
        for (int j2 = 0; j2 < 6; ++j2) vw = (jj == j2) ? accW[j2] : vw;
        const float inv = (t == 0) ? 1.0f : 1.0f/(sqrtf(ssk) + EPSV);
        const float gk  = 1.0f/(1.0f + expf(-(shk*inv + skk)));
        const int cw = cg*6 + jj, cglob = c0 + cw;
        const float rold = r[kk*H_DIM + cglob];
        const float x    = v*inv + keyV_lds[kk][cw] + vw;   // hU_norm + keyV + sW
        const float cand = (x >= 0.f) ? x : alpha_v * x;
        g_h[nxt][b][kk][cglob] = fmaf(gk, cand, rold*inv);  // raw h_new (pre-norm)
      }
    }
    bar_t += WPG;
    group_barrier(&g_bar[G*32], bar_t);
  }

  // ---- final pred row (t = T-1) from buf[T&1] == buf[0] ----
  if (g == 0) {
    const float* qbase2 = fe + (size_t)(T_STEPS-1)*B_SZ*H_DIM;
    for (int bi = 0; bi < M_B; ++bi) {
      const int b = b0 + bi;
      const float* r = &g_h[0][b][0][0];
      const float* q = qbase2 + (size_t)b*H_DIM;
      float ss[K_BLK]={0,0,0,0,0}, qh[K_BLK]={0,0,0,0,0};
      #pragma unroll
      for (int i = 0; i < 3; ++i) {
        const int d = (dl << 2) + i*256;
        const float4 qv = *(const float4*)(q + d);
        #pragma unroll
        for (int k = 0; k < K_BLK; ++k) {
          const float4 rk = *(const float4*)(r + k*H_DIM + d);
          ss[k] = fmaf(rk.x, rk.x, fmaf(rk.y, rk.y, fmaf(rk.z, rk.z, fmaf(rk.w, rk.w, ss[k]))));
          qh[k] = fmaf(qv.x, rk.x, fmaf(qv.y, rk.y, fmaf(qv.z, rk.z, fmaf(qv.w, rk.w, qh[k]))));
        }
      }
      #pragma unroll
      for (int off = 1; off < 64; off <<= 1) {
        #pragma unroll
        for (int k = 0; k < K_BLK; ++k) {
          ss[k] += __shfl_xor(ss[k], off);
          qh[k] += __shfl_xor(qh[k], off);
        }
      }
      if (tid < L_OUT) {
        float p = bout[tid];
        #pragma unroll
        for (int k = 0; k < K_BLK; ++k)
          p = fmaf(qh[k] / (sqrtf(ss[k]) + EPSV), Wout[k*L_OUT + tid], p);
        out[(size_t)((T_STEPS-1)*B_SZ + b)*L_OUT + tid] = p;
      }
    }
  }
}

extern "C" void kernel_launch(void* const* d_in, const int* in_sizes, int n_in,
                              void* d_out, int out_size, void* d_ws, size_t ws_size,
                              hipStream_t stream) {
  const float* fs    = (const float*)d_in[0];
  const float* fe    = (const float*)d_in[1];
  const float* keys  = (const float*)d_in[2];
  const float* U     = (const float*)d_in[3];
  const float* V     = (const float*)d_in[4];
  const float* W     = (const float*)d_in[5];
  const float* alpha = (const float*)d_in[6];
  const float* Wout  = (const float*)d_in[7];
  const float* bout  = (const float*)d_in[8];
  float* out = (float*)d_out;

  reset_bar<<<1, NGROUP*32, 0, stream>>>();
  // 256 blocks, 149KB LDS each -> exactly 1 block/CU on 256 CUs: all co-resident,
  // so the per-group atomic barriers cannot deadlock.
  entnet_main<<<dim3(NWG), dim3(NTHR), 0, stream>>>(fs, fe, keys, U, V, W,
                                                    alpha, Wout, bout, out);
}

// Round 7
// 12502.196 us; speedup vs baseline: 1.2503x; 1.2503x over previous
//
#include <hip/hip_runtime.h>
#include <math.h>

// EntNetHead: T=256 sequential steps, B=64 batches, H=768, K=5 blocks, L=3.
// Persistent kernel, 256 WGs (1/CU via 159.5KB LDS), 8 batch-groups x 32
// column-slice WGs. U,W column slices + keys + pred head cached in LDS once.
// h state (raw, pre-norm) double-buffered in a __device__ global; cross-WG h
// moves via sc0 sc1 (L1+L2-bypass) loads/stores to the MALL/L3 coherence
// point; barrier = atomicAdd + relaxed poll (NO __threadfence -> no L2 wb/inv
// storm, which was 73% of R2's 15.6ms).
// R6 = R5 resubmitted byte-identical (R5 never executed: container failure).
// R5 deltas vs R4 (never benched - acquisition timeout):
//  - Register diet: keys (60 VGPR) and Wout/bout (18 VGPR) moved to LDS;
//    U/W LDS padding dropped (free for 16B-contiguous reads, m136). R4's
//    budget was ~280 VGPR > the 256 cap at 2 waves/SIMD -> hot-loop spills.
//    New peak ~200. LDS = 163,368B <= 163,840 cap, still 1 WG/CU.
//  - (from R4) rule-#18 fix: sched_barrier(0) after every counted s_waitcnt.
//  - (from R4) 512 threads: two 256-thread halves own batches {h,h+2,h+4,h+6}.
// Arithmetic is order-identical to R2 -> absmax must be exactly 0.015625.

#define T_STEPS 256
#define B_SZ    64
#define H_DIM   768
#define K_BLK   5
#define L_OUT   3
#define EPSV    1e-8f

#define NGROUP  8
#define WPG     32
#define M_B     8
#define COLS    24
#define NWG     (NGROUP*WPG)   // 256 == #CUs
#define NTHR    512            // 8 waves: 2 halves x 4 waves

typedef float f32x4 __attribute__((ext_vector_type(4)));

__device__ __align__(16) float g_h[2][B_SZ][K_BLK][H_DIM];  // raw h, dbuf, 1.97MB
__device__ unsigned int g_bar[NGROUP*32];

__global__ void reset_bar() {
  int i = threadIdx.x;
  if (i < NGROUP*32) g_bar[i] = 0u;
}

// --- coherence-point (MALL/L3) access: bypass L1 (sc0) and L2 (sc1) ---
__device__ __forceinline__ f32x4 ld4_cg(const float* p) {
  f32x4 r;
  asm volatile("global_load_dwordx4 %0, %1, off sc0 sc1" : "=&v"(r) : "v"(p) : "memory");
  return r;
}
__device__ __forceinline__ float ld1_cg(const float* p) {
  float r;
  asm volatile("global_load_dword %0, %1, off sc0 sc1" : "=&v"(r) : "v"(p) : "memory");
  return r;
}
__device__ __forceinline__ void st1_cg(float* p, float v) {
  asm volatile("global_store_dword %0, %1, off sc0 sc1" :: "v"(p), "v"(v) : "memory");
}
__device__ __forceinline__ f32x4 ld4c(const float* p) {   // normal cached load
  f32x4 r;
  asm volatile("global_load_dwordx4 %0, %1, off" : "=&v"(r) : "v"(p) : "memory");
  return r;
}
// Counted wait + scheduler fence. The sched_barrier is MANDATORY (rule #18):
// without it hipcc hoists register-only consumers above the inline waitcnt.
#define WAITVM(N) do { \
    asm volatile("s_waitcnt vmcnt(" #N ")" ::: "memory"); \
    __builtin_amdgcn_sched_barrier(0); \
  } while (0)

// Barrier: __syncthreads drains vmcnt(0) -> all sc1 stores are at L3 before
// thread-0's flag-add (device-scope, executes at L3). Consumers observe flag,
// then re-read h with sc0sc1 loads -> no cache maintenance needed, ever.
__device__ __forceinline__ void group_barrier(unsigned int* cnt, unsigned int target) {
  asm volatile("s_waitcnt vmcnt(0)" ::: "memory");
  __syncthreads();
  if (threadIdx.x == 0) {
    atomicAdd(cnt, 1u);
    while (__hip_atomic_load(cnt, __ATOMIC_RELAXED, __HIP_MEMORY_SCOPE_AGENT) < target)
      __builtin_amdgcn_s_sleep(2);
  }
  __syncthreads();
}

// load one batch's h rows (15 x dwordx4 + 1 scalar rold) into RST/ROLD
#define LOAD_R(RST, ROLD, RB)                                              \
  {                                                                        \
    _Pragma("unroll")                                                      \
    for (int i = 0; i < 3; ++i) {                                          \
      const int d = (dl << 2) + i*256;                                     \
      _Pragma("unroll")                                                    \
      for (int k = 0; k < K_BLK; ++k)                                      \
        RST[i][k] = ld4_cg((RB) + k*H_DIM + d);                            \
    }                                                                      \
    ROLD = ld1_cg((RB) + kk0*H_DIM + cglob0);                              \
  }

// One batch: issue s/q (cached) + prefetch next owned batch's h (if DO_PF),
// counted wait leaves exactly the 16 prefetch loads in flight, then compute.
// vmcnt invariant at WAITVM(16): the NEWEST 16 VMEM ops are the prefetch
// block; all older ops (pred/h stores, s/q, current h) drain. Extra older ops
// (e.g. g==0's pred store) don't break the invariant - they just drain too.
// No compiler-generated global LOADS exist in this loop (keys/Wout/bout are
// LDS now), so no compiler vmcnt insertion can interfere.
#define BATCH_BODY(BI, RC, OC, RN, ON, DO_PF, WN)                          \
  {                                                                        \
    const int b = b0 + (BI);                                               \
    const float* s = sbase + (size_t)b*H_DIM;                              \
    const float* q = qbase + (size_t)b*H_DIM;                              \
    f32x4 sv4[3], qv4[3];                                                  \
    _Pragma("unroll")                                                      \
    for (int i = 0; i < 3; ++i) {                                          \
      const int d = (dl << 2) + i*256;                                     \
      sv4[i] = ld4c(s + d);                                                \
      qv4[i] = ld4c(q + d);                                                \
    }                                                                      \
    if (DO_PF) {                                                           \
      const float* rbn = &g_h[cur][b0 + (BI) + 2][0][0];                   \
      LOAD_R(RN, ON, rbn);                                                 \
    }                                                                      \
    WAITVM(WN);                                                            \
    float ss[K_BLK]={0,0,0,0,0}, sh[K_BLK]={0,0,0,0,0};                    \
    float qh[K_BLK]={0,0,0,0,0}, sk[K_BLK]={0,0,0,0,0};                    \
    _Pragma("unroll")                                                      \
    for (int i = 0; i < 3; ++i) {                                          \
      const int d = (dl << 2) + i*256;                                     \
      const f32x4 sv = sv4[i], qv = qv4[i];                                \
      _Pragma("unroll")                                                    \
      for (int k = 0; k < K_BLK; ++k) {                                    \
        const f32x4 rk = RC[i][k];                                         \
        const f32x4 kk4 = *(const f32x4*)&keys_lds[k][d];                  \
        ss[k] = fmaf(rk[0],rk[0], fmaf(rk[1],rk[1], fmaf(rk[2],rk[2], fmaf(rk[3],rk[3], ss[k])))); \
        sh[k] = fmaf(sv[0],rk[0], fmaf(sv[1],rk[1], fmaf(sv[2],rk[2], fmaf(sv[3],rk[3], sh[k])))); \
        qh[k] = fmaf(qv[0],rk[0], fmaf(qv[1],rk[1], fmaf(qv[2],rk[2], fmaf(qv[3],rk[3], qh[k])))); \
        sk[k] = fmaf(sv[0],kk4[0],fmaf(sv[1],kk4[1],fmaf(sv[2],kk4[2],fmaf(sv[3],kk4[3],sk[k])))); \
      }                                                                    \
    }                                                                      \
    _Pragma("unroll")                                                      \
    for (int off = 1; off < 64; off <<= 1) {                               \
      _Pragma("unroll")                                                    \
      for (int k = 0; k < K_BLK; ++k) {                                    \
        ss[k] += __shfl_xor(ss[k], off);                                   \
        sh[k] += __shfl_xor(sh[k], off);                                   \
        qh[k] += __shfl_xor(qh[k], off);                                   \
        sk[k] += __shfl_xor(sk[k], off);                                   \
      }                                                                    \
    }                                                                      \
    if (g == 0 && t > 0 && htid < L_OUT) {                                 \
      float p0 = pred_lds[0], p1 = pred_lds[1], p2 = pred_lds[2];          \
      _Pragma("unroll")                                                    \
      for (int k = 0; k < K_BLK; ++k) {                                    \
        const float sc = qh[k] / (sqrtf(ss[k]) + EPSV);                    \
        p0 = fmaf(sc, pred_lds[3 + k*L_OUT + 0], p0);                      \
        p1 = fmaf(sc, pred_lds[3 + k*L_OUT + 1], p1);                      \
        p2 = fmaf(sc, pred_lds[3 + k*L_OUT + 2], p2);                      \
      }                                                                    \
      const float pv = (htid == 0) ? p0 : ((htid == 1) ? p1 : p2);         \
      out[(size_t)((t-1)*B_SZ + b)*L_OUT + htid] = pv;                     \
    }                                                                      \
    float acc[K_BLK][6] = {}; float accW[6] = {};                          \
    _Pragma("unroll")                                                      \
    for (int i = 0; i < 3; ++i) {                                          \
      const int d = (dl << 2) + i*256;                                     \
      const f32x4 sv = sv4[i];                                             \
      _Pragma("unroll")                                                    \
      for (int j = 0; j < 6; ++j) {                                        \
        const int c = cg*6 + j;                                            \
        const f32x4 u = *(const f32x4*)&U_lds[c][d];                       \
        _Pragma("unroll")                                                  \
        for (int k = 0; k < K_BLK; ++k) {                                  \
          const f32x4 rk = RC[i][k];                                       \
          acc[k][j] = fmaf(rk[0],u[0], fmaf(rk[1],u[1], fmaf(rk[2],u[2], fmaf(rk[3],u[3], acc[k][j])))); \
        }                                                                  \
        const f32x4 w4 = *(const f32x4*)&W_lds[c][d];                      \
        accW[j] = fmaf(sv[0],w4[0], fmaf(sv[1],w4[1], fmaf(sv[2],w4[2], fmaf(sv[3],w4[3], accW[j])))); \
      }                                                                    \
    }                                                                      \
    _Pragma("unroll")                                                      \
    for (int off = 1; off < 64; off <<= 1) {                               \
      _Pragma("unroll")                                                    \
      for (int j = 0; j < 6; ++j) {                                        \
        _Pragma("unroll")                                                  \
        for (int k = 0; k < K_BLK; ++k) acc[k][j] += __shfl_xor(acc[k][j], off); \
        accW[j] += __shfl_xor(accW[j], off);                               \
      }                                                                    \
    }                                                                      \
    if (dl < 30) {                                                         \
      float v = 0.f, vw = 0.f, ssk = 0.f, shk = 0.f, skk = 0.f;            \
      _Pragma("unroll")                                                    \
      for (int k2 = 0; k2 < K_BLK; ++k2) {                                 \
        _Pragma("unroll")                                                  \
        for (int j2 = 0; j2 < 6; ++j2)                                     \
          v = (kk0 == k2 && jj0 == j2) ? acc[k2][j2] : v;                  \
        ssk = (kk0 == k2) ? ss[k2] : ssk;                                  \
        shk = (kk0 == k2) ? sh[k2] : shk;                                  \
        skk = (kk0 == k2) ? sk[k2] : skk;                                  \
      }                                                                    \
      _Pragma("unroll")                                                    \
      for (int j2 = 0; j2 < 6; ++j2) vw = (jj0 == j2) ? accW[j2] : vw;     \
      const float inv = (t == 0) ? 1.0f : 1.0f/(sqrtf(ssk) + EPSV);        \
      const float gk  = 1.0f/(1.0f + expf(-(shk*inv + skk)));              \
      const float x    = v*inv + keyV_lds[kk0][cw0] + vw;                  \
      const float cand = (x >= 0.f) ? x : alpha_v * x;                     \
      st1_cg(&g_h[nxt][b][kk0][cglob0], fmaf(gk, cand, (OC)*inv));         \
    }                                                                      \
  }

extern "C" __global__ void __launch_bounds__(NTHR, 2)
entnet_main(const float* __restrict__ fs, const float* __restrict__ fe,
            const float* __restrict__ keys, const float* __restrict__ U,
            const float* __restrict__ V, const float* __restrict__ W,
            const float* __restrict__ alpha, const float* __restrict__ Wout,
            const float* __restrict__ bout, float* __restrict__ out)
{
  // LDS budget: 73728*2 + 15360 + 480 + 72 = 163,368 B <= 163,840 (1 WG/CU)
  __shared__ float U_lds[COLS][H_DIM];
  __shared__ float W_lds[COLS][H_DIM];
  __shared__ float keys_lds[K_BLK][H_DIM];
  __shared__ float keyV_lds[K_BLK][COLS];
  __shared__ float pred_lds[3 + K_BLK*L_OUT];   // [0..2]=bout, [3+k*3+l]=Wout

  const int tid  = threadIdx.x;
  const int wgid = blockIdx.x;
  const int G    = wgid & 7;
  const int g    = wgid >> 3;
  const int c0   = g * COLS;
  const int b0   = G * M_B;
  const float alpha_v = alpha[0];
  const int half = tid >> 8;             // 0: batches {0,2,4,6}; 1: {1,3,5,7}
  const int htid = tid & 255;
  const int dl = tid & 63, cg = (tid >> 6) & 3;
  // lane constants for the 30-lane writeback (clamped for dl>=30 dummy loads)
  const int kk0 = (dl < 30) ? dl/6 : 0;
  const int jj0 = (dl < 30) ? dl - (dl/6)*6 : 0;
  const int cw0 = cg*6 + jj0;
  const int cglob0 = c0 + cw0;

  // ---- prologue ----
  for (int idx = tid; idx < COLS*H_DIM; idx += NTHR) {
    int d = idx / COLS, c = idx % COLS;
    U_lds[c][d] = U[(size_t)d*H_DIM + c0 + c];
    W_lds[c][d] = W[(size_t)d*H_DIM + c0 + c];
  }
  for (int idx = tid; idx < K_BLK*H_DIM; idx += NTHR)
    keys_lds[idx / H_DIM][idx % H_DIM] = keys[idx];
  if (tid < 3 + K_BLK*L_OUT)
    pred_lds[tid] = (tid < 3) ? bout[tid] : Wout[tid - 3];
  if (tid < K_BLK*COLS) {
    int k = tid / COLS, c = tid % COLS;
    float acc = 0.f;
    for (int d = 0; d < H_DIM; ++d)
      acc = fmaf(keys[k*H_DIM + d], V[(size_t)d*H_DIM + c0 + c], acc);
    keyV_lds[k][c] = acc;
  }
  // h init via coherent stores (read cross-XCD after the first barrier)
  for (int idx = tid; idx < M_B*K_BLK*COLS; idx += NTHR) {
    int bi = idx / (K_BLK*COLS); int rr = idx % (K_BLK*COLS);
    int k = rr / COLS, c = rr % COLS;
    st1_cg(&g_h[0][b0+bi][k][c0 + c], keys[k*H_DIM + c0 + c]);
  }

  unsigned int bar_t = WPG;
  group_barrier(&g_bar[G*32], bar_t);   // also covers the LDS prologue writes

  f32x4 rA[3][K_BLK], rB[3][K_BLK];
  float oA, oB;

  // ---- main recurrence: each half runs its 4 batches independently ----
  for (int t = 0; t < T_STEPS; ++t) {
    const int cur = t & 1, nxt = cur ^ 1;
    const float* sbase = fs + (size_t)t*B_SZ*H_DIM;
    const float* qbase = fe + (size_t)(t > 0 ? (t-1) : 0)*B_SZ*H_DIM;

    {  // first owned batch: cold-load, then pipeline
      const float* rb0 = &g_h[cur][b0 + half][0][0];
      LOAD_R(rA, oA, rb0);
    }
    BATCH_BODY(half + 0, rA, oA, rB, oB, 1, 16);
    BATCH_BODY(half + 2, rB, oB, rA, oA, 1, 16);
    BATCH_BODY(half + 4, rA, oA, rB, oB, 1, 16);
    BATCH_BODY(half + 6, rB, oB, rA, oA, 0, 0);

    bar_t += WPG;
    group_barrier(&g_bar[G*32], bar_t);
  }

  // ---- final pred row (t = T-1) from buf[T&1] == buf[0] ----
  if (g == 0) {
    const float* qb2 = fe + (size_t)(T_STEPS-1)*B_SZ*H_DIM;
    for (int bi2 = 0; bi2 < 4; ++bi2) {
      const int b = b0 + 2*bi2 + half;
      const float* rb = &g_h[0][b][0][0];
      const float* q = qb2 + (size_t)b*H_DIM;
      f32x4 rv[3][K_BLK], qv4[3];
      #pragma unroll
      for (int i = 0; i < 3; ++i) {
        const int d = (dl << 2) + i*256;
        qv4[i] = ld4c(q + d);
        #pragma unroll
        for (int k = 0; k < K_BLK; ++k)
          rv[i][k] = ld4_cg(rb + k*H_DIM + d);
      }
      WAITVM(0);
      float ss[K_BLK]={0,0,0,0,0}, qh[K_BLK]={0,0,0,0,0};
      #pragma unroll
      for (int i = 0; i < 3; ++i) {
        const f32x4 qv = qv4[i];
        #pragma unroll
        for (int k = 0; k < K_BLK; ++k) {
          const f32x4 rk = rv[i][k];
          ss[k] = fmaf(rk[0],rk[0], fmaf(rk[1],rk[1], fmaf(rk[2],rk[2], fmaf(rk[3],rk[3], ss[k]))));
          qh[k] = fmaf(qv[0],rk[0], fmaf(qv[1],rk[1], fmaf(qv[2],rk[2], fmaf(qv[3],rk[3], qh[k]))));
        }
      }
      #pragma unroll
      for (int off = 1; off < 64; off <<= 1) {
        #pragma unroll
        for (int k = 0; k < K_BLK; ++k) {
          ss[k] += __shfl_xor(ss[k], off);
          qh[k] += __shfl_xor(qh[k], off);
        }
      }
      if (htid < L_OUT) {
        float p0 = pred_lds[0], p1 = pred_lds[1], p2 = pred_lds[2];
        #pragma unroll
        for (int k = 0; k < K_BLK; ++k) {
          const float sc = qh[k] / (sqrtf(ss[k]) + EPSV);
          p0 = fmaf(sc, pred_lds[3 + k*L_OUT + 0], p0);
          p1 = fmaf(sc, pred_lds[3 + k*L_OUT + 1], p1);
          p2 = fmaf(sc, pred_lds[3 + k*L_OUT + 2], p2);
        }
        const float pv = (htid == 0) ? p0 : ((htid == 1) ? p1 : p2);
        out[(size_t)((T_STEPS-1)*B_SZ + b)*L_OUT + htid] = pv;
      }
    }
  }
}

extern "C" void kernel_launch(void* const* d_in, const int* in_sizes, int n_in,
                              void* d_out, int out_size, void* d_ws, size_t ws_size,
                              hipStream_t stream) {
  const float* fs    = (const float*)d_in[0];
  const float* fe    = (const float*)d_in[1];
  const float* keys  = (const float*)d_in[2];
  const float* U     = (const float*)d_in[3];
  const float* V     = (const float*)d_in[4];
  const float* W     = (const float*)d_in[5];
  const float* alpha = (const float*)d_in[6];
  const float* Wout  = (const float*)d_in[7];
  const float* bout  = (const float*)d_in[8];
  float* out = (float*)d_out;

  reset_bar<<<1, NGROUP*32, 0, stream>>>();
  // 256 blocks, 159.5KB LDS each -> exactly 1 block/CU on 256 CUs: all
  // co-resident, so the per-group atomic barriers cannot deadlock.
  entnet_main<<<dim3(NWG), dim3(NTHR), 0, stream>>>(fs, fe, keys, U, V, W,
                                                    alpha, Wout, bout, out);
}